// Round 4
// baseline (827.043 us; speedup 1.0000x reference)
//
#include <hip/hip_runtime.h>

namespace {

constexpr int Bn = 32, Cn = 8, Hn = 512, In = 512;
constexpr size_t HI = (size_t)Hn * In;
constexpr float SC = 1.0f / 5000.0f;

using s16x8 = __attribute__((ext_vector_type(8))) short;
using f32x4 = __attribute__((ext_vector_type(4))) float;

__device__ __forceinline__ float actf(float x) { return fminf(1.0f, fmaxf(-1.0f, x)); }

__device__ __forceinline__ unsigned short f2bf(float f) {   // RNE f32->bf16
    unsigned u = __builtin_bit_cast(unsigned, f);
    u += 0x7FFFu + ((u >> 16) & 1u);
    return (unsigned short)(u >> 16);
}

__device__ __forceinline__ void async16(const void* g, void* l) {
    __builtin_amdgcn_global_load_lds(
        (const __attribute__((address_space(1))) unsigned*)g,
        (__attribute__((address_space(3))) unsigned*)l, 16, 0, 0);
}

// LDS map: T0 = 64KB resident [64 row][512 col] bf16 tile (XOR-swizzled),
//          BCH = 2 x 32KB B-chunks [4 kc][512 col][16B],
//          ACH = 2 x 4KB  A-chunks [4 kc][64 row][16B] (G1 only).
constexpr int T0_OFF  = 0;
constexpr int BCH_OFF = 65536;
constexpr int ACH_OFF = 131072;
constexpr int LDS_SZ  = 139264;

#define CFENCE asm volatile("" ::: "memory")

// 64x512 = A(64x512) @ B(512 cols x 512 k)^T, K streamed in 16 chunks of 32.
// A: resident in T0 (swizzled) or staged from global (ASTG, G1).
// Counted-vmcnt double-buffered B staging; raw barriers (no full drain).
template<bool ASTG>
__device__ __forceinline__ void run_gemm(char* lds,
    const char* Bg, const char* Ag, int tid, int wid, int l15, int kq,
    f32x4 acc[4][4])
{
    const int col0 = wid * 64;
    // prologue: chunk 0 -> buf 0
    #pragma unroll
    for (int i = 0; i < 4; ++i)
        async16(Bg + (size_t)tid * 1024 + i * 16, lds + BCH_OFF + i * 8192 + tid * 16);
    if (ASTG) {
        const int g = tid & 255;   // waves 4-7 duplicate (benign) -> uniform vmcnt
        async16(Ag + (size_t)(g & 63) * 1024 + (g >> 6) * 16, lds + ACH_OFF + g * 16);
    }
    int buf = 0;
    #pragma unroll 1
    for (int ks = 0; ks < 16; ++ks) {
        if (ks < 15) {
            const char* bs = Bg + (ks + 1) * 64;
            const int nb = buf ^ 1;
            #pragma unroll
            for (int i = 0; i < 4; ++i)
                async16(bs + (size_t)tid * 1024 + i * 16,
                        lds + BCH_OFF + nb * 32768 + i * 8192 + tid * 16);
            if (ASTG) {
                const int g = tid & 255;
                async16(Ag + (size_t)(g & 63) * 1024 + (ks + 1) * 64 + (g >> 6) * 16,
                        lds + ACH_OFF + nb * 4096 + g * 16);
                asm volatile("s_waitcnt vmcnt(5)" ::: "memory");  // prefetch stays in flight
            } else {
                asm volatile("s_waitcnt vmcnt(4)" ::: "memory");
            }
        } else {
            asm volatile("s_waitcnt vmcnt(0)" ::: "memory");
        }
        __builtin_amdgcn_s_barrier(); CFENCE;

        s16x8 a[4], b[4];
        #pragma unroll
        for (int m = 0; m < 4; ++m) {
            if (ASTG) {
                a[m] = *(const s16x8*)(lds + ACH_OFF + buf * 4096 + kq * 1024 + (m * 16 + l15) * 16);
            } else {
                const int row = m * 16 + l15;
                const int nat = ks * 64 + kq * 16;
                a[m] = *(const s16x8*)(lds + T0_OFF + row * 1024 + (nat ^ ((row & 7) << 4)));
            }
        }
        #pragma unroll
        for (int n = 0; n < 4; ++n)
            b[n] = *(const s16x8*)(lds + BCH_OFF + buf * 32768 + kq * 8192 + (col0 + n * 16 + l15) * 16);
        #pragma unroll
        for (int m = 0; m < 4; ++m)
            #pragma unroll
            for (int n = 0; n < 4; ++n)
                acc[m][n] = __builtin_amdgcn_mfma_f32_16x16x32_bf16(a[m], b[n], acc[m][n], 0, 0, 0);
        CFENCE; __builtin_amdgcn_s_barrier(); CFENCE;   // all waves done with buf
        buf ^= 1;
    }
}

// Fused: G1(Wpe@pset) -> G2(p_lin) -> G3(z_lin) -> channel sum -> fc1 -> fc2.
// Grid: 256 wgs = 32 b x 8 h-tiles of 64 rows; 512 threads (8 waves x 64-col slice).
__global__ __launch_bounds__(512, 2) void mega(
    const unsigned short* __restrict__ xst,    // [B*C][i][k] bf16
    const unsigned short* __restrict__ Wpeb,
    const unsigned short* __restrict__ plwb, const float* __restrict__ plb,
    const unsigned short* __restrict__ zlwb, const float* __restrict__ zlb,
    const unsigned short* __restrict__ f1wb, const float* __restrict__ f1b,
    const unsigned short* __restrict__ f2wb, const float* __restrict__ f2b,
    const float* __restrict__ zrow, const float* __restrict__ input,
    float* __restrict__ out)
{
    __shared__ __align__(16) char lds[LDS_SZ];
    const int tid = threadIdx.x;
    const int wid = tid >> 6, lane = tid & 63;
    const int l15 = lane & 15, kq = lane >> 4;
    const int bb = blockIdx.x & 31;
    const int h0 = (blockIdx.x >> 5) * 64;
    const int col0 = wid * 64;

    auto t0w = [&](int row, int col, unsigned short v) {
        *(unsigned short*)(lds + T0_OFF + row * 1024 + ((col * 2) ^ ((row & 7) << 4))) = v;
    };

    f32x4 comb[4][4] = {};

    #pragma unroll 1
    for (int c = 0; c < Cn; ++c) {
        {   // ---- G1: T0 = act(Wpe[h-tile] @ xst[b,c]^T) ----
            f32x4 acc[4][4] = {};
            run_gemm<true>(lds, (const char*)xst + (size_t)(bb * Cn + c) * HI * 2,
                           (const char*)Wpeb + (size_t)h0 * 1024, tid, wid, l15, kq, acc);
            #pragma unroll
            for (int m = 0; m < 4; ++m)
                #pragma unroll
                for (int n = 0; n < 4; ++n) {
                    const int col = col0 + n * 16 + l15;
                    #pragma unroll
                    for (int j = 0; j < 4; ++j)
                        t0w(m * 16 + kq * 4 + j, col, f2bf(actf(acc[m][n][j])));
                }
            __syncthreads();
        }
        {   // ---- G2: tp = act(T0 @ plw^T + plb); comb += tp; T0 = act(zrow*tp) ----
            f32x4 acc[4][4] = {};
            run_gemm<false>(lds, (const char*)plwb, nullptr, tid, wid, l15, kq, acc);
            float bn[4], zrv[4][4];
            #pragma unroll
            for (int n = 0; n < 4; ++n) bn[n] = plb[col0 + n * 16 + l15];
            #pragma unroll
            for (int m = 0; m < 4; ++m)
                #pragma unroll
                for (int j = 0; j < 4; ++j)
                    zrv[m][j] = zrow[h0 + m * 16 + kq * 4 + j];
            #pragma unroll
            for (int m = 0; m < 4; ++m)
                #pragma unroll
                for (int n = 0; n < 4; ++n) {
                    const int col = col0 + n * 16 + l15;
                    #pragma unroll
                    for (int j = 0; j < 4; ++j) {
                        float tp = actf(acc[m][n][j] + bn[n]);
                        comb[m][n][j] += tp;
                        t0w(m * 16 + kq * 4 + j, col, f2bf(actf(zrv[m][j] * tp)));
                    }
                }
            __syncthreads();
        }
        {   // ---- G3: comb += act(T0 @ zlw^T + zlb) ----
            f32x4 acc[4][4] = {};
            run_gemm<false>(lds, (const char*)zlwb, nullptr, tid, wid, l15, kq, acc);
            float bn[4];
            #pragma unroll
            for (int n = 0; n < 4; ++n) bn[n] = zlb[col0 + n * 16 + l15];
            #pragma unroll
            for (int m = 0; m < 4; ++m)
                #pragma unroll
                for (int n = 0; n < 4; ++n)
                    #pragma unroll
                    for (int j = 0; j < 4; ++j)
                        comb[m][n][j] += actf(acc[m][n][j] + bn[n]);
            // T0 reads finished inside run_gemm's final barrier; next G1 write is safe.
        }
    }

    // ---- comb += x[b,0]/5000; T0 = bf16(comb) ----
    #pragma unroll
    for (int m = 0; m < 4; ++m)
        #pragma unroll
        for (int n = 0; n < 4; ++n) {
            const int col = col0 + n * 16 + l15;
            #pragma unroll
            for (int j = 0; j < 4; ++j) {
                const int row = m * 16 + kq * 4 + j;
                float x0v = input[((size_t)(bb * Cn) * Hn + h0 + row) * In + col];
                t0w(row, col, f2bf(comb[m][n][j] + x0v * SC));
            }
        }
    __syncthreads();

    {   // ---- fc1: T0 = relu(T0 @ f1w^T + f1b) ----
        f32x4 acc[4][4] = {};
        run_gemm<false>(lds, (const char*)f1wb, nullptr, tid, wid, l15, kq, acc);
        float bn[4];
        #pragma unroll
        for (int n = 0; n < 4; ++n) bn[n] = f1b[col0 + n * 16 + l15];
        #pragma unroll
        for (int m = 0; m < 4; ++m)
            #pragma unroll
            for (int n = 0; n < 4; ++n) {
                const int col = col0 + n * 16 + l15;
                #pragma unroll
                for (int j = 0; j < 4; ++j)
                    t0w(m * 16 + kq * 4 + j, col, f2bf(fmaxf(acc[m][n][j] + bn[n], 0.0f)));
            }
        __syncthreads();
    }
    {   // ---- fc2: out = T0 @ f2w^T + f2b (fp32) ----
        f32x4 acc[4][4] = {};
        run_gemm<false>(lds, (const char*)f2wb, nullptr, tid, wid, l15, kq, acc);
        float bn[4];
        #pragma unroll
        for (int n = 0; n < 4; ++n) bn[n] = f2b[col0 + n * 16 + l15];
        #pragma unroll
        for (int m = 0; m < 4; ++m)
            #pragma unroll
            for (int n = 0; n < 4; ++n) {
                const int col = col0 + n * 16 + l15;
                #pragma unroll
                for (int j = 0; j < 4; ++j) {
                    const int row = m * 16 + kq * 4 + j;
                    out[((size_t)bb * Hn + h0 + row) * In + col] = acc[m][n][j] + bn[n];
                }
            }
    }
}

// xst[bc][i][k] = bf16( x[bc][k][i] * act(mask[k][i]) / 5000 )
__global__ __launch_bounds__(256) void transpose_mask(
    const float* __restrict__ x, const float* __restrict__ mask,
    unsigned short* __restrict__ xst)
{
    __shared__ float t[64][65];
    const int bc = blockIdx.z;
    const int i0 = blockIdx.x * 64, k0 = blockIdx.y * 64;
    const int r4 = threadIdx.x >> 6, cc = threadIdx.x & 63;
    const float* xp = x + (size_t)bc * HI;
    #pragma unroll
    for (int it = 0; it < 16; ++it) {
        int kl = it * 4 + r4;
        size_t g = (size_t)(k0 + kl) * In + i0 + cc;
        t[kl][cc] = xp[g] * (actf(mask[g]) * SC);
    }
    __syncthreads();
    unsigned short* op = xst + (size_t)bc * HI;
    #pragma unroll
    for (int it = 0; it < 16; ++it) {
        int il = it * 4 + r4;
        op[(size_t)(i0 + il) * Hn + k0 + cc] = f2bf(t[cc][il]);
    }
}

__global__ __launch_bounds__(256) void prep_wpe_bf(
    const float* __restrict__ Wp, const float* __restrict__ Wpd,
    unsigned short* __restrict__ o)
{
    int idx = blockIdx.x * 256 + threadIdx.x;
    int i = idx >> 9, j = idx & 511;
    o[idx] = f2bf(Wp[idx] + (i == j ? Wpd[i] : 0.0f));
}

__global__ __launch_bounds__(256) void conv_bf(
    const float* __restrict__ s, unsigned short* __restrict__ o)
{
    int idx = blockIdx.x * 256 + threadIdx.x;
    o[idx] = f2bf(s[idx]);
}

__global__ __launch_bounds__(64) void rowsum(
    const float* __restrict__ W, float* __restrict__ zr)
{
    int h = blockIdx.x, l = threadIdx.x;
    float s = 0.0f;
    for (int k = l; k < Hn; k += 64) s += W[h * Hn + k];
    #pragma unroll
    for (int off = 32; off; off >>= 1) s += __shfl_down(s, off, 64);
    if (!l) zr[h] = s;
}

} // namespace

extern "C" void kernel_launch(void* const* d_in, const int* in_sizes, int n_in,
                              void* d_out, int out_size, void* d_ws, size_t ws_size,
                              hipStream_t stream)
{
    const float* input  = (const float*)d_in[0];
    const float* p_mask = (const float*)d_in[1];
    const float* Wp     = (const float*)d_in[2];
    const float* Wpd    = (const float*)d_in[3];
    const float* Wzp    = (const float*)d_in[4];
    const float* plw    = (const float*)d_in[5];
    const float* plb    = (const float*)d_in[6];
    const float* zlw    = (const float*)d_in[7];
    const float* zlb    = (const float*)d_in[8];
    const float* f1w    = (const float*)d_in[9];
    const float* f1b    = (const float*)d_in[10];
    const float* f2w    = (const float*)d_in[11];
    const float* f2b    = (const float*)d_in[12];

    constexpr size_t WB = 512 * 512 * 2;   // one bf16 weight
    char* w = (char*)d_ws;
    auto alloc = [&](size_t bytes) { char* p = w; w += (bytes + 255) & ~255ull; return p; };

    unsigned short* Wpeb = (unsigned short*)alloc(WB);
    unsigned short* plwb = (unsigned short*)alloc(WB);
    unsigned short* zlwb = (unsigned short*)alloc(WB);
    unsigned short* f1wb = (unsigned short*)alloc(WB);
    unsigned short* f2wb = (unsigned short*)alloc(WB);
    float*          zrw  = (float*)alloc(512 * 4);
    unsigned short* xst  = (unsigned short*)alloc((size_t)Bn * Cn * HI * 2);  // 134 MB

    prep_wpe_bf<<<512 * 512 / 256, 256, 0, stream>>>(Wp, Wpd, Wpeb);
    conv_bf<<<1024, 256, 0, stream>>>(plw, plwb);
    conv_bf<<<1024, 256, 0, stream>>>(zlw, zlwb);
    conv_bf<<<1024, 256, 0, stream>>>(f1w, f1wb);
    conv_bf<<<1024, 256, 0, stream>>>(f2w, f2wb);
    rowsum<<<512, 64, 0, stream>>>(Wzp, zrw);

    transpose_mask<<<dim3(8, 8, Bn * Cn), 256, 0, stream>>>(input, p_mask, xst);

    mega<<<Bn * 8, 512, 0, stream>>>(xst, Wpeb, plwb, plb, zlwb, zlb,
                                     f1wb, f1b, f2wb, f2b, zrw, input,
                                     (float*)d_out);
}

// Round 5
// 814.385 us; speedup vs baseline: 1.0155x; 1.0155x over previous
//
#include <hip/hip_runtime.h>

namespace {

constexpr int Bn = 32, Cn = 8, Hn = 512, In = 512;
constexpr size_t HI = (size_t)Hn * In;
constexpr float SC = 1.0f / 5000.0f;

using s16x8 = __attribute__((ext_vector_type(8))) short;
using f32x4 = __attribute__((ext_vector_type(4))) float;

__device__ __forceinline__ float actf(float x) { return fminf(1.0f, fmaxf(-1.0f, x)); }

__device__ __forceinline__ unsigned short f2bf(float f) {   // RNE f32->bf16
    unsigned u = __builtin_bit_cast(unsigned, f);
    u += 0x7FFFu + ((u >> 16) & 1u);
    return (unsigned short)(u >> 16);
}

__device__ __forceinline__ void async16(const void* g, void* l) {
    __builtin_amdgcn_global_load_lds(
        (const __attribute__((address_space(1))) unsigned*)g,
        (__attribute__((address_space(3))) unsigned*)l, 16, 0, 0);
}

// Stage a 64-row x 32-k bf16 chunk (4KB) into LDS layout [kq 4][row 64][16B].
// Source row-major, row stride 1024B. One async16 per thread (256 thr).
__device__ __forceinline__ void stage64(const char* g, char* l, int tid, int ks) {
    async16(g + (size_t)(tid & 63) * 1024 + ks * 64 + (tid >> 6) * 16, l + tid * 16);
}
// Stage a 128-row x 32-k chunk (8KB) into [kq 4][row 128][16B]. Two async16.
__device__ __forceinline__ void stage128(const char* g, char* l, int tid, int ks) {
    const size_t ro = (size_t)(tid & 127) * 1024;
    const int kb = ks * 64 + (tid >> 7) * 16;
    async16(g + ro + kb,      l + tid * 16);
    async16(g + ro + kb + 32, l + 4096 + tid * 16);
}

#define VMCNT0 asm volatile("s_waitcnt vmcnt(0)" ::: "memory")

// ---------------------------------------------------------------------------
// 128x128-tile GEMM, 4 waves, BK=32, 2-phase counted prefetch, K=512.
// C[z] = A[z] @ Bt[z]^T (strides in elements; 0 = shared operand).
// EPI 0: bf16(act(acc))        (G1, no bias)
//     1: bf16(relu(acc+bias))  (fc1)
//     2: fp32(acc+bias)        (fc2)
// ---------------------------------------------------------------------------
template<int EPI>
__global__ __launch_bounds__(256, 4) void gemm128(
    const unsigned short* __restrict__ A, size_t sAe,
    const unsigned short* __restrict__ Bt, size_t sBe,
    const float* __restrict__ bias,
    unsigned short* __restrict__ outb, float* __restrict__ outf, size_t sOe)
{
    __shared__ __align__(16) char lds[2][16384];    // [buf][A 8KB | B 8KB]
    const int tid = threadIdx.x, wid = tid >> 6, lane = tid & 63;
    const int l15 = lane & 15, kq = lane >> 4, wr = wid >> 1, wc = wid & 1;
    const size_t z = blockIdx.z;
    const char* Ab = (const char*)(A + z * sAe) + (size_t)blockIdx.y * 131072;
    const char* Bb = (const char*)(Bt + z * sBe) + (size_t)blockIdx.x * 131072;

    f32x4 acc[4][4] = {};
    stage128(Ab, lds[0], tid, 0);
    stage128(Bb, lds[0] + 8192, tid, 0);
    VMCNT0;
    __builtin_amdgcn_s_barrier();
    int cur = 0;
    #pragma unroll 1
    for (int ks = 0; ks < 16; ++ks) {
        if (ks < 15) {
            stage128(Ab, lds[cur ^ 1], tid, ks + 1);
            stage128(Bb, lds[cur ^ 1] + 8192, tid, ks + 1);
        }
        s16x8 a[4], b[4];
        #pragma unroll
        for (int m = 0; m < 4; ++m)
            a[m] = *(const s16x8*)(lds[cur] + kq * 2048 + (wr * 64 + m * 16 + l15) * 16);
        #pragma unroll
        for (int n = 0; n < 4; ++n)
            b[n] = *(const s16x8*)(lds[cur] + 8192 + kq * 2048 + (wc * 64 + n * 16 + l15) * 16);
        #pragma unroll
        for (int m = 0; m < 4; ++m)
            #pragma unroll
            for (int n = 0; n < 4; ++n)
                acc[m][n] = __builtin_amdgcn_mfma_f32_16x16x32_bf16(a[m], b[n], acc[m][n], 0, 0, 0);
        VMCNT0;
        __builtin_amdgcn_s_barrier();
        cur ^= 1;
    }
    const int r0 = blockIdx.y * 128 + wr * 64 + kq * 4;
    const int c0 = blockIdx.x * 128 + wc * 64 + l15;
    #pragma unroll
    for (int n = 0; n < 4; ++n) {
        const int col = c0 + n * 16;
        const float bs = (EPI == 0) ? 0.0f : bias[col];
        #pragma unroll
        for (int m = 0; m < 4; ++m)
            #pragma unroll
            for (int j = 0; j < 4; ++j) {
                const size_t idx = z * sOe + (size_t)(r0 + m * 16 + j) * 512 + col;
                float v = acc[m][n][j];
                if (EPI == 0)      outb[idx] = f2bf(actf(v));
                else if (EPI == 1) outb[idx] = f2bf(fmaxf(v + bs, 0.0f));
                else               outf[idx] = v + bs;
            }
    }
}

// ---------------------------------------------------------------------------
// 64x128-tile c-looped GEMM (G2/G3), 4 waves, BK=32, 2-phase prefetch.
// Block owns (b, 64-row h-tile, 128 cols); loops c=0..7 holding channel sums
// in registers.
//  G2 (G3=false): per c: tp = act(acc+plb); comb += tp;
//                 tzin[b,c] = bf16(act(zrow*tp));
//                 final:   combp = comb + x0*SC            (fp32)
//  G3 (G3=true):  per c: comb += act(acc+zlb);
//                 final:   aux[b*512+h] = bf16(combp + comb)
// ---------------------------------------------------------------------------
template<bool G3>
__global__ __launch_bounds__(256, 4) void gemm64(
    const unsigned short* __restrict__ Ab0,   // tpact / tzin  [b,c,h,i]
    const unsigned short* __restrict__ Bw,    // plwb / zlwb
    const float* __restrict__ bias,
    const float* __restrict__ zrow,           // G2 only
    const float* __restrict__ input,          // G2 only (x0 = channel 0)
    float* __restrict__ combp,                // G2: write; G3: read
    unsigned short* __restrict__ aux)         // G2: tzin; G3: comb bf16
{
    __shared__ __align__(16) char lds[2][12288];   // [buf][A 4KB | B 8KB]
    const int tid = threadIdx.x, wid = tid >> 6, lane = tid & 63;
    const int l15 = lane & 15, kq = lane >> 4, wr = wid >> 1, wc = wid & 1;
    const int b = blockIdx.y >> 3, h0 = (blockIdx.y & 7) * 64;
    const int n0 = blockIdx.x * 128;
    const char* Bb = (const char*)Bw + (size_t)n0 * 1024;
    const char* Abase = (const char*)Ab0 + ((size_t)b * Cn * HI + (size_t)h0 * 512) * 2;

    f32x4 comb[2][4] = {};
    float zr[2][4];
    if (!G3) {
        #pragma unroll
        for (int m = 0; m < 2; ++m)
            #pragma unroll
            for (int j = 0; j < 4; ++j)
                zr[m][j] = zrow[h0 + wr * 32 + m * 16 + kq * 4 + j];
    }

    stage64(Abase, lds[0], tid, 0);
    stage128(Bb, lds[0] + 4096, tid, 0);
    VMCNT0;
    __builtin_amdgcn_s_barrier();
    int cur = 0;

    #pragma unroll 1
    for (int c = 0; c < Cn; ++c) {
        const char* Ac = Abase + (size_t)c * HI * 2;
        f32x4 acc[2][4] = {};
        #pragma unroll 1
        for (int ks = 0; ks < 16; ++ks) {
            if (ks < 15) {
                stage64(Ac, lds[cur ^ 1], tid, ks + 1);
                stage128(Bb, lds[cur ^ 1] + 4096, tid, ks + 1);
            } else if (c < Cn - 1) {
                stage64(Ac + HI * 2, lds[cur ^ 1], tid, 0);
                stage128(Bb, lds[cur ^ 1] + 4096, tid, 0);
            }
            s16x8 a[2], bfr[4];
            #pragma unroll
            for (int m = 0; m < 2; ++m)
                a[m] = *(const s16x8*)(lds[cur] + kq * 1024 + (wr * 32 + m * 16 + l15) * 16);
            #pragma unroll
            for (int n = 0; n < 4; ++n)
                bfr[n] = *(const s16x8*)(lds[cur] + 4096 + kq * 2048 + (wc * 64 + n * 16 + l15) * 16);
            #pragma unroll
            for (int m = 0; m < 2; ++m)
                #pragma unroll
                for (int n = 0; n < 4; ++n)
                    acc[m][n] = __builtin_amdgcn_mfma_f32_16x16x32_bf16(a[m], bfr[n], acc[m][n], 0, 0, 0);
            VMCNT0;
            __builtin_amdgcn_s_barrier();
            cur ^= 1;
        }
        // per-c epilogue (registers + global stores only; no LDS hazard)
        #pragma unroll
        for (int n = 0; n < 4; ++n) {
            const int col = n0 + wc * 64 + n * 16 + l15;
            const float bs = bias[col];
            #pragma unroll
            for (int m = 0; m < 2; ++m)
                #pragma unroll
                for (int j = 0; j < 4; ++j) {
                    float v = actf(acc[m][n][j] + bs);
                    comb[m][n][j] += v;
                    if (!G3) {
                        const int r = h0 + wr * 32 + m * 16 + kq * 4 + j;
                        aux[(size_t)(b * Cn + c) * HI + (size_t)r * 512 + col] =
                            f2bf(actf(zr[m][j] * v));
                    }
                }
        }
    }

    #pragma unroll
    for (int n = 0; n < 4; ++n) {
        const int col = n0 + wc * 64 + n * 16 + l15;
        #pragma unroll
        for (int m = 0; m < 2; ++m)
            #pragma unroll
            for (int j = 0; j < 4; ++j) {
                const int r = h0 + wr * 32 + m * 16 + kq * 4 + j;
                const size_t ci = (size_t)b * HI + (size_t)r * 512 + col;
                if (!G3)
                    combp[ci] = comb[m][n][j] +
                                input[(size_t)b * Cn * HI + (size_t)r * 512 + col] * SC;
                else
                    aux[(size_t)(b * 512 + r) * 512 + col] = f2bf(combp[ci] + comb[m][n][j]);
            }
    }
}

// xst[bc][i][k] = bf16( x[bc][k][i] * act(mask[k][i]) / 5000 )
__global__ __launch_bounds__(256) void transpose_mask(
    const float* __restrict__ x, const float* __restrict__ mask,
    unsigned short* __restrict__ xst)
{
    __shared__ float t[64][65];
    const int bc = blockIdx.z;
    const int i0 = blockIdx.x * 64, k0 = blockIdx.y * 64;
    const int r4 = threadIdx.x >> 6, cc = threadIdx.x & 63;
    const float* xp = x + (size_t)bc * HI;
    #pragma unroll
    for (int it = 0; it < 16; ++it) {
        int kl = it * 4 + r4;
        size_t g = (size_t)(k0 + kl) * In + i0 + cc;
        t[kl][cc] = xp[g] * (actf(mask[g]) * SC);
    }
    __syncthreads();
    unsigned short* op = xst + (size_t)bc * HI;
    #pragma unroll
    for (int it = 0; it < 16; ++it) {
        int il = it * 4 + r4;
        op[(size_t)(i0 + il) * Hn + k0 + cc] = f2bf(t[cc][il]);
    }
}

__global__ __launch_bounds__(256) void prep_wpe_bf(
    const float* __restrict__ Wp, const float* __restrict__ Wpd,
    unsigned short* __restrict__ o)
{
    int idx = blockIdx.x * 256 + threadIdx.x;
    int i = idx >> 9, j = idx & 511;
    o[idx] = f2bf(Wp[idx] + (i == j ? Wpd[i] : 0.0f));
}

__global__ __launch_bounds__(256) void conv_bf(
    const float* __restrict__ s, unsigned short* __restrict__ o)
{
    int idx = blockIdx.x * 256 + threadIdx.x;
    o[idx] = f2bf(s[idx]);
}

__global__ __launch_bounds__(64) void rowsum(
    const float* __restrict__ W, float* __restrict__ zr)
{
    int h = blockIdx.x, l = threadIdx.x;
    float s = 0.0f;
    for (int k = l; k < Hn; k += 64) s += W[h * Hn + k];
    #pragma unroll
    for (int off = 32; off; off >>= 1) s += __shfl_down(s, off, 64);
    if (!l) zr[h] = s;
}

} // namespace

extern "C" void kernel_launch(void* const* d_in, const int* in_sizes, int n_in,
                              void* d_out, int out_size, void* d_ws, size_t ws_size,
                              hipStream_t stream)
{
    const float* input  = (const float*)d_in[0];
    const float* p_mask = (const float*)d_in[1];
    const float* Wp     = (const float*)d_in[2];
    const float* Wpd    = (const float*)d_in[3];
    const float* Wzp    = (const float*)d_in[4];
    const float* plw    = (const float*)d_in[5];
    const float* plb    = (const float*)d_in[6];
    const float* zlw    = (const float*)d_in[7];
    const float* zlb    = (const float*)d_in[8];
    const float* f1w    = (const float*)d_in[9];
    const float* f1b    = (const float*)d_in[10];
    const float* f2w    = (const float*)d_in[11];
    const float* f2b    = (const float*)d_in[12];

    constexpr size_t WB = 512 * 512 * 2;   // one bf16 weight matrix
    char* w = (char*)d_ws;
    auto alloc = [&](size_t bytes) { char* p = w; w += (bytes + 255) & ~255ull; return p; };

    unsigned short* Wpeb  = (unsigned short*)alloc(WB);
    unsigned short* plwb  = (unsigned short*)alloc(WB);
    unsigned short* zlwb  = (unsigned short*)alloc(WB);
    unsigned short* f1wb  = (unsigned short*)alloc(WB);
    unsigned short* f2wb  = (unsigned short*)alloc(WB);
    float*          zrw   = (float*)alloc(512 * 4);
    unsigned short* xst   = (unsigned short*)alloc((size_t)Bn * Cn * HI * 2);  // 134 MB
    unsigned short* tpact = (unsigned short*)alloc((size_t)Bn * Cn * HI * 2);  // 134 MB
    unsigned short* tzin  = (unsigned short*)alloc((size_t)Bn * Cn * HI * 2);  // 134 MB
    float*          combp = (float*)alloc((size_t)Bn * HI * 4);                // 33.5 MB
    unsigned short* combb = (unsigned short*)alloc((size_t)Bn * HI * 2);       // 16.8 MB
    unsigned short* out1  = (unsigned short*)alloc((size_t)Bn * HI * 2);       // 16.8 MB

    prep_wpe_bf<<<512 * 512 / 256, 256, 0, stream>>>(Wp, Wpd, Wpeb);
    conv_bf<<<1024, 256, 0, stream>>>(plw, plwb);
    conv_bf<<<1024, 256, 0, stream>>>(zlw, zlwb);
    conv_bf<<<1024, 256, 0, stream>>>(f1w, f1wb);
    conv_bf<<<1024, 256, 0, stream>>>(f2w, f2wb);
    rowsum<<<512, 64, 0, stream>>>(Wzp, zrw);

    // xst = bf16(x^T * act(mask)/5000)
    transpose_mask<<<dim3(8, 8, Bn * Cn), 256, 0, stream>>>(input, p_mask, xst);

    // G1: tpact[bc] = act(Wpe @ xst[bc]^T)
    gemm128<0><<<dim3(4, 4, Bn * Cn), 256, 0, stream>>>(
        Wpeb, 0, xst, HI, nullptr, tpact, nullptr, HI);

    // G2: c-loop; comb=sum_c tp; tzin; combp = comb + x0*SC
    gemm64<false><<<dim3(4, 256), 256, 0, stream>>>(
        tpact, plwb, plb, zrw, input, combp, tzin);

    // G3: c-loop; combb = bf16(combp + sum_c tz)
    gemm64<true><<<dim3(4, 256), 256, 0, stream>>>(
        tzin, zlwb, zlb, nullptr, nullptr, combp, combb);

    // fc1: out1 = relu(combb @ f1w^T + f1b)
    gemm128<1><<<dim3(4, 128, 1), 256, 0, stream>>>(
        combb, 0, f1wb, 0, f1b, out1, nullptr, 0);
    // fc2: out = out1 @ f2w^T + f2b   (fp32)
    gemm128<2><<<dim3(4, 128, 1), 256, 0, stream>>>(
        out1, 0, f2wb, 0, f2b, nullptr, (float*)d_out, 0);
}

// Round 6
// 800.944 us; speedup vs baseline: 1.0326x; 1.0168x over previous
//
#include <hip/hip_runtime.h>

namespace {

constexpr int Bn = 32, Cn = 8, Hn = 512, In = 512;
constexpr size_t HI = (size_t)Hn * In;
constexpr float SC = 1.0f / 5000.0f;

using s16x8 = __attribute__((ext_vector_type(8))) short;
using f32x4 = __attribute__((ext_vector_type(4))) float;

__device__ __forceinline__ float actf(float x) { return fminf(1.0f, fmaxf(-1.0f, x)); }

__device__ __forceinline__ unsigned short f2bf(float f) {   // RNE f32->bf16
    unsigned u = __builtin_bit_cast(unsigned, f);
    u += 0x7FFFu + ((u >> 16) & 1u);
    return (unsigned short)(u >> 16);
}
__device__ __forceinline__ float bf2f(unsigned short h) {
    return __builtin_bit_cast(float, (unsigned)h << 16);
}

__device__ __forceinline__ void async16(const void* g, void* l) {
    __builtin_amdgcn_global_load_lds(
        (const __attribute__((address_space(1))) unsigned*)g,
        (__attribute__((address_space(3))) unsigned*)l, 16, 0, 0);
}

// Stage a 128-row x 32-k bf16 chunk (8KB) into LDS [kq 4][row 128][16B].
// Row-major source, row stride 1024B. 2 async16 per thread (256 thr).
__device__ __forceinline__ void stage128(const char* g, char* l, int tid, int ks) {
    const size_t ro = (size_t)(tid & 127) * 1024;
    const int kb = ks * 64 + (tid >> 7) * 16;
    async16(g + ro + kb,      l + tid * 16);
    async16(g + ro + kb + 32, l + 4096 + tid * 16);
}

// ---------------------------------------------------------------------------
// 128x128-tile GEMM, 4 waves, BK=32, K=512. Triple-buffered LDS with counted
// vmcnt(4): tile t+1's loads stay in flight across the barrier (T4); one
// barrier per K-step. C[z] = A[z] @ Bt[z]^T.
// EPI 0: out0=bf16(act(acc))                         (G1, no bias)
//     1: tp=act(acc+b); out0=bf16(tp); out1=bf16(act(zrow[r]*tp))  (G2)
//     2: out0=bf16(act(acc+b))                        (G3)
//     3: out0=bf16(relu(acc+b))                       (fc1)
//     4: outf=acc+b (fp32)                            (fc2)
// ---------------------------------------------------------------------------
template<int EPI>
__global__ __launch_bounds__(256, 3) void gemm128(
    const unsigned short* __restrict__ A, size_t sAe,
    const unsigned short* __restrict__ Bt, size_t sBe,
    const float* __restrict__ bias,
    const float* __restrict__ zrow,
    unsigned short* __restrict__ out0,
    unsigned short* __restrict__ out1,
    float* __restrict__ outf, size_t sOe)
{
    __shared__ __align__(16) char lds[3][16384];    // [buf][A 8KB | B 8KB]
    const int tid = threadIdx.x, wid = tid >> 6, lane = tid & 63;
    const int l15 = lane & 15, kq = lane >> 4, wr = wid >> 1, wc = wid & 1;
    const size_t z = blockIdx.z;
    const char* Ab = (const char*)(A + z * sAe) + (size_t)blockIdx.y * 131072;
    const char* Bb = (const char*)(Bt + z * sBe) + (size_t)blockIdx.x * 131072;

    char* p0 = &lds[0][0];
    char* p1 = &lds[1][0];
    char* p2 = &lds[2][0];

    f32x4 acc[4][4] = {};

    // prologue: tiles 0,1 in flight (8 loads/thread)
    stage128(Ab, p0, tid, 0); stage128(Bb, p0 + 8192, tid, 0);
    stage128(Ab, p1, tid, 1); stage128(Bb, p1 + 8192, tid, 1);

    auto compute = [&](const char* p) {
        s16x8 a[4], b[4];
        #pragma unroll
        for (int m = 0; m < 4; ++m)
            a[m] = *(const s16x8*)(p + kq * 2048 + (wr * 64 + m * 16 + l15) * 16);
        #pragma unroll
        for (int n = 0; n < 4; ++n)
            b[n] = *(const s16x8*)(p + 8192 + kq * 2048 + (wc * 64 + n * 16 + l15) * 16);
        #pragma unroll
        for (int m = 0; m < 4; ++m)
            #pragma unroll
            for (int n = 0; n < 4; ++n)
                acc[m][n] = __builtin_amdgcn_mfma_f32_16x16x32_bf16(a[m], b[n], acc[m][n], 0, 0, 0);
    };

    #pragma unroll 1
    for (int ks = 0; ks < 15; ++ks) {
        // tile ks complete (all but newest 4 loads done); tile ks+1 in flight
        asm volatile("s_waitcnt vmcnt(4)" ::: "memory");
        __builtin_amdgcn_s_barrier();
        asm volatile("" ::: "memory");
        if (ks < 14) {                               // stage tile ks+2 -> p2
            stage128(Ab, p2, tid, ks + 2);
            stage128(Bb, p2 + 8192, tid, ks + 2);
        }
        compute(p0);
        char* t = p0; p0 = p1; p1 = p2; p2 = t;      // rotate
    }
    asm volatile("s_waitcnt vmcnt(0)" ::: "memory");
    __builtin_amdgcn_s_barrier();
    asm volatile("" ::: "memory");
    compute(p0);                                     // tile 15

    // epilogue: C/D map col=lane&15, row=(lane>>4)*4+j
    const int r0 = blockIdx.y * 128 + wr * 64 + kq * 4;
    const int c0 = blockIdx.x * 128 + wc * 64 + l15;
    #pragma unroll
    for (int n = 0; n < 4; ++n) {
        const int col = c0 + n * 16;
        const float bs = (EPI == 0) ? 0.0f : bias[col];
        #pragma unroll
        for (int m = 0; m < 4; ++m)
            #pragma unroll
            for (int j = 0; j < 4; ++j) {
                const int r = r0 + m * 16 + j;
                const size_t idx = z * sOe + (size_t)r * 512 + col;
                float v = acc[m][n][j];
                if (EPI == 0) {
                    out0[idx] = f2bf(actf(v));
                } else if (EPI == 1) {
                    float tp = actf(v + bs);
                    out0[idx] = f2bf(tp);
                    out1[idx] = f2bf(actf(zrow[r] * tp));
                } else if (EPI == 2) {
                    out0[idx] = f2bf(actf(v + bs));
                } else if (EPI == 3) {
                    out0[idx] = f2bf(fmaxf(v + bs, 0.0f));
                } else {
                    outf[idx] = v + bs;
                }
            }
    }
}

// comb[b] = bf16( x0[b]/5000 + sum_c tp[b,c] + sum_c tz[b,c] )
__global__ __launch_bounds__(256) void reduce_both(
    const unsigned short* __restrict__ tp,
    const unsigned short* __restrict__ tz,
    const float* __restrict__ x0,
    unsigned short* __restrict__ comb)
{
    size_t idx = (size_t)blockIdx.x * 256 + threadIdx.x;   // float4 slot
    size_t b = idx >> 16;                                  // / (HI/4)
    size_t p = (idx & 65535) * 4;
    float4 xv = *(const float4*)&x0[(b * Cn) * HI + p];
    float s0 = xv.x * SC, s1 = xv.y * SC, s2 = xv.z * SC, s3 = xv.w * SC;
    #pragma unroll
    for (int c = 0; c < Cn; ++c) {
        size_t q = (b * Cn + c) * HI + p;
        ushort4 a = *(const ushort4*)&tp[q];
        ushort4 d = *(const ushort4*)&tz[q];
        s0 += bf2f(a.x) + bf2f(d.x);
        s1 += bf2f(a.y) + bf2f(d.y);
        s2 += bf2f(a.z) + bf2f(d.z);
        s3 += bf2f(a.w) + bf2f(d.w);
    }
    ushort4 o;
    o.x = f2bf(s0); o.y = f2bf(s1); o.z = f2bf(s2); o.w = f2bf(s3);
    *(ushort4*)&comb[b * HI + p] = o;
}

// xst[bc][i][k] = bf16( x[bc][k][i] * act(mask[k][i]) / 5000 )
__global__ __launch_bounds__(256) void transpose_mask(
    const float* __restrict__ x, const float* __restrict__ mask,
    unsigned short* __restrict__ xst)
{
    __shared__ float t[64][65];
    const int bc = blockIdx.z;
    const int i0 = blockIdx.x * 64, k0 = blockIdx.y * 64;
    const int r4 = threadIdx.x >> 6, cc = threadIdx.x & 63;
    const float* xp = x + (size_t)bc * HI;
    #pragma unroll
    for (int it = 0; it < 16; ++it) {
        int kl = it * 4 + r4;
        size_t g = (size_t)(k0 + kl) * In + i0 + cc;
        t[kl][cc] = xp[g] * (actf(mask[g]) * SC);
    }
    __syncthreads();
    unsigned short* op = xst + (size_t)bc * HI;
    #pragma unroll
    for (int it = 0; it < 16; ++it) {
        int il = it * 4 + r4;
        op[(size_t)(i0 + il) * Hn + k0 + cc] = f2bf(t[cc][il]);
    }
}

__global__ __launch_bounds__(256) void prep_wpe_bf(
    const float* __restrict__ Wp, const float* __restrict__ Wpd,
    unsigned short* __restrict__ o)
{
    int idx = blockIdx.x * 256 + threadIdx.x;
    int i = idx >> 9, j = idx & 511;
    o[idx] = f2bf(Wp[idx] + (i == j ? Wpd[i] : 0.0f));
}

__global__ __launch_bounds__(256) void conv_bf(
    const float* __restrict__ s, unsigned short* __restrict__ o)
{
    int idx = blockIdx.x * 256 + threadIdx.x;
    o[idx] = f2bf(s[idx]);
}

__global__ __launch_bounds__(64) void rowsum(
    const float* __restrict__ W, float* __restrict__ zr)
{
    int h = blockIdx.x, l = threadIdx.x;
    float s = 0.0f;
    for (int k = l; k < Hn; k += 64) s += W[h * Hn + k];
    #pragma unroll
    for (int off = 32; off; off >>= 1) s += __shfl_down(s, off, 64);
    if (!l) zr[h] = s;
}

} // namespace

extern "C" void kernel_launch(void* const* d_in, const int* in_sizes, int n_in,
                              void* d_out, int out_size, void* d_ws, size_t ws_size,
                              hipStream_t stream)
{
    const float* input  = (const float*)d_in[0];
    const float* p_mask = (const float*)d_in[1];
    const float* Wp     = (const float*)d_in[2];
    const float* Wpd    = (const float*)d_in[3];
    const float* Wzp    = (const float*)d_in[4];
    const float* plw    = (const float*)d_in[5];
    const float* plb    = (const float*)d_in[6];
    const float* zlw    = (const float*)d_in[7];
    const float* zlb    = (const float*)d_in[8];
    const float* f1w    = (const float*)d_in[9];
    const float* f1b    = (const float*)d_in[10];
    const float* f2w    = (const float*)d_in[11];
    const float* f2b    = (const float*)d_in[12];

    constexpr size_t WB = 512 * 512 * 2;   // one bf16 weight matrix
    char* w = (char*)d_ws;
    auto alloc = [&](size_t bytes) { char* p = w; w += (bytes + 255) & ~255ull; return p; };

    unsigned short* Wpeb  = (unsigned short*)alloc(WB);
    unsigned short* plwb  = (unsigned short*)alloc(WB);
    unsigned short* zlwb  = (unsigned short*)alloc(WB);
    unsigned short* f1wb  = (unsigned short*)alloc(WB);
    unsigned short* f2wb  = (unsigned short*)alloc(WB);
    float*          zrw   = (float*)alloc(512 * 4);
    unsigned short* combb = (unsigned short*)alloc((size_t)Bn * HI * 2);   // 16.8 MB
    unsigned short* out1  = (unsigned short*)alloc((size_t)Bn * HI * 2);   // 16.8 MB

    size_t fixedB = (size_t)(w - (char*)d_ws);
    int chunk = 32;
    while (chunk > 1 &&
           fixedB + 4ull * (size_t)chunk * Cn * HI * 2 + 4096 > ws_size)
        chunk >>= 1;
    const size_t CB = (size_t)chunk * Cn * HI * 2;
    unsigned short* xst   = (unsigned short*)alloc(CB);   // reused for tz
    unsigned short* tpact = (unsigned short*)alloc(CB);
    unsigned short* tpb   = (unsigned short*)alloc(CB);
    unsigned short* tzin  = (unsigned short*)alloc(CB);
    unsigned short* tzb   = xst;

    prep_wpe_bf<<<512 * 512 / 256, 256, 0, stream>>>(Wp, Wpd, Wpeb);
    conv_bf<<<1024, 256, 0, stream>>>(plw, plwb);
    conv_bf<<<1024, 256, 0, stream>>>(zlw, zlwb);
    conv_bf<<<1024, 256, 0, stream>>>(f1w, f1wb);
    conv_bf<<<1024, 256, 0, stream>>>(f2w, f2wb);
    rowsum<<<512, 64, 0, stream>>>(Wzp, zrw);

    for (int b0 = 0; b0 < Bn; b0 += chunk) {
        const int nc = chunk * Cn;
        const float* inp_c = input + (size_t)b0 * Cn * HI;

        // xst = bf16(x^T * act(mask)/5000)
        transpose_mask<<<dim3(8, 8, nc), 256, 0, stream>>>(inp_c, p_mask, xst);
        // G1: tpact[bc] = act(Wpe @ xst[bc]^T)
        gemm128<0><<<dim3(4, 4, nc), 256, 0, stream>>>(
            Wpeb, 0, xst, HI, nullptr, nullptr, tpact, nullptr, nullptr, HI);
        // G2: tp = act(tpact @ plw^T + plb); tzin = act(zrow*tp)
        gemm128<1><<<dim3(4, 4, nc), 256, 0, stream>>>(
            tpact, HI, plwb, 0, plb, zrw, tpb, tzin, nullptr, HI);
        // G3: tz = act(tzin @ zlw^T + zlb)
        gemm128<2><<<dim3(4, 4, nc), 256, 0, stream>>>(
            tzin, HI, zlwb, 0, zlb, nullptr, tzb, nullptr, nullptr, HI);
        // comb = x0/5000 + sum_c tp + sum_c tz
        reduce_both<<<chunk * 256, 256, 0, stream>>>(
            tpb, tzb, inp_c, combb + (size_t)b0 * HI);
    }

    // fc1: out1 = relu(combb @ f1w^T + f1b)
    gemm128<3><<<dim3(4, 128, 1), 256, 0, stream>>>(
        combb, 0, f1wb, 0, f1b, nullptr, out1, nullptr, nullptr, 0);
    // fc2: out = out1 @ f2w^T + f2b   (fp32)
    gemm128<4><<<dim3(4, 128, 1), 256, 0, stream>>>(
        out1, 0, f2wb, 0, f2b, nullptr, nullptr, nullptr, (float*)d_out, 0);
}